// Round 8
// baseline (283.635 us; speedup 1.0000x reference)
//
#include <hip/hip_runtime.h>

#define N_ROWS 16384
#define DIM 256
#define MARGINF 0.3f
#define CH 1024
#define NTILE 64          // 16-col tiles per chunk
#define LOG2E 1.44269504089f

typedef float f32x4 __attribute__((ext_vector_type(4)));
typedef long lng;

__device__ __forceinline__ float fexp2(float x) {
#if __has_builtin(__builtin_amdgcn_exp2f)
  return __builtin_amdgcn_exp2f(x);
#else
  return exp2f(x);
#endif
}

// ------------------------------------------------------------------
// float -> OCP e4m3fn (manual fallback)
// ------------------------------------------------------------------
__device__ __forceinline__ unsigned char to_e4m3(float f) {
  unsigned u = __float_as_uint(f);
  unsigned sign = (u >> 24) & 0x80u;
  float a = fabsf(f);
  if (a >= 448.0f) return (unsigned char)(sign | 0x7eu);
  if (a < 0.015625f) {
    int q = (int)(a * 512.0f + 0.5f);
    return (unsigned char)(sign | (unsigned)q);
  }
  int e;
  float m = frexpf(a, &e);
  float mant = 2.0f * m;
  int e8 = e - 1;
  int mb = (int)(mant * 8.0f + 0.5f) - 8;
  if (mb == 8) { mb = 0; ++e8; if (e8 > 8) return (unsigned char)(sign | 0x7eu); }
  return (unsigned char)(sign | (unsigned)((e8 + 7) << 3) | (unsigned)mb);
}

__device__ __forceinline__ unsigned int pack4_e4m3(float a, float b, float c, float d) {
#if __has_builtin(__builtin_amdgcn_cvt_pk_fp8_f32)
  int lo = __builtin_amdgcn_cvt_pk_fp8_f32(a, b, 0, false);
  int r = __builtin_amdgcn_cvt_pk_fp8_f32(c, d, lo, true);
  return (unsigned int)r;
#else
  return (unsigned int)to_e4m3(a) | ((unsigned int)to_e4m3(b) << 8) |
         ((unsigned int)to_e4m3(c) << 16) | ((unsigned int)to_e4m3(d) << 24);
#endif
}

// ------------------------------------------------------------------
// Kernel 1: norms + exact fp32 diag cosine + fp8 rows.
// x-side pre-scaled by log2(e) so the GEMM's exp(S) = exp2(S').
// ------------------------------------------------------------------
__global__ __launch_bounds__(256) void normalize_kernel(
    const float* __restrict__ x, const float* __restrict__ y,
    unsigned int* __restrict__ xn8, unsigned int* __restrict__ yn8,
    float* __restrict__ diagF) {
  const int wid = threadIdx.x >> 6;
  const int lane = threadIdx.x & 63;
  const int r = blockIdx.x * 4 + wid;  // 0..16383
  const float4 vx = *reinterpret_cast<const float4*>(x + (size_t)r * DIM + lane * 4);
  const float4 vy = *reinterpret_cast<const float4*>(y + (size_t)r * DIM + lane * 4);
  float sx = vx.x * vx.x + vx.y * vx.y + vx.z * vx.z + vx.w * vx.w;
  float sy = vy.x * vy.x + vy.y * vy.y + vy.z * vy.z + vy.w * vy.w;
  float sxy = vx.x * vy.x + vx.y * vy.y + vx.z * vy.z + vx.w * vy.w;
  #pragma unroll
  for (int off = 32; off; off >>= 1) {
    sx += __shfl_xor(sx, off);
    sy += __shfl_xor(sy, off);
    sxy += __shfl_xor(sxy, off);
  }
  const float scx = LOG2E / fmaxf(sqrtf(sx), 1e-8f);   // log2e folded into A
  const float scy = 1.0f / fmaxf(sqrtf(sy), 1e-8f);
  if (lane == 0) diagF[r] = sxy * (scx / LOG2E) * scy;
  xn8[(size_t)r * 64 + lane] = pack4_e4m3(vx.x * scx, vx.y * scx, vx.z * scx, vx.w * scx);
  yn8[(size_t)r * 64 + lane] = pack4_e4m3(vy.x * scy, vy.y * scy, vy.z * scy, vy.w * scy);
}

// ------------------------------------------------------------------
// Kernel 2: barrier-free fp8 GEMM + exp2.
// Each WAVE independently owns 64 rows x 1024-col chunk. A in regs
// (a[4][8]); B fragments loaded global->reg per 16-col tile (L2-
// resident: 256 KB/XCD chunk), double-buffered in registers. 32 MFMA
// per tile, exp2 epilogue, per-wave partial writes. No LDS, no
// __syncthreads -> waves free-run; epilogue of one wave hides under
// MFMA of the others.
// ------------------------------------------------------------------
__global__ __launch_bounds__(256, 3) void gemm_exp_kernel(
    const unsigned char* __restrict__ xn8, const unsigned char* __restrict__ yn8,
    float* __restrict__ diag8, float* __restrict__ rowpart,
    float* __restrict__ colpartW, float* __restrict__ rowsumG,
    float* __restrict__ colsumG, int use_scratch) {
  const int tid = threadIdx.x;
  const int lane = tid & 63;
  const int wid = tid >> 6;
  const int grp = lane >> 4, li = lane & 15;

  // job mapping: XCD-local, 2 col-chunks per XCD, band-major
  const int bid = blockIdx.x;          // 0..1023
  const int xcd = bid & 7;
  const int p = bid >> 3;              // 0..127
  const int chunk = xcd * 2 + (p >> 6);          // 0..15
  const int band = ((p & 63) << 2) + wid;        // 0..255
  const int rowBase = band * 64;
  const int colBase = chunk * CH;

  // ---- A: 64 rows x 256 K fp8 -> 32 lng (64 VGPR) ----
  lng a[4][8];
  #pragma unroll
  for (int m = 0; m < 4; ++m)
    #pragma unroll
    for (int ks = 0; ks < 8; ++ks)
      a[m][ks] = *reinterpret_cast<const lng*>(
          xn8 + (unsigned)((rowBase + m * 16 + li) * DIM + ks * 32 + grp * 8));

  float rsum[4][4];
  #pragma unroll
  for (int m = 0; m < 4; ++m)
    #pragma unroll
    for (int j = 0; j < 4; ++j) rsum[m][j] = 0.0f;

  // B double buffer in registers; col for this lane = base + li
  lng bc[8], bn[8];
  #pragma unroll
  for (int ks = 0; ks < 8; ++ks)
    bc[ks] = *reinterpret_cast<const lng*>(
        yn8 + (unsigned)((colBase + li) * DIM + ks * 32 + grp * 8));

  const bool diagWave = (chunk == (band >> 4));
  const int diagT0 = (band & 15) << 2;   // 4 diag tiles start here (t>>2 == band&15)

  for (int t = 0; t < NTILE; ++t) {
    if (t + 1 < NTILE) {
      const unsigned nb = (unsigned)((colBase + (t + 1) * 16 + li) * DIM + grp * 8);
      #pragma unroll
      for (int ks = 0; ks < 8; ++ks)
        bn[ks] = *reinterpret_cast<const lng*>(yn8 + nb + ks * 32);
    }

    f32x4 acc[4];
    #pragma unroll
    for (int m = 0; m < 4; ++m) acc[m] = (f32x4)(0.0f);

    __builtin_amdgcn_s_setprio(1);
    #pragma unroll
    for (int ks = 0; ks < 8; ++ks)
      #pragma unroll
      for (int m = 0; m < 4; ++m)
        acc[m] = __builtin_amdgcn_mfma_f32_16x16x32_fp8_fp8(a[m][ks], bc[ks], acc[m], 0, 0, 0);
    __builtin_amdgcn_s_setprio(0);

    // ---- epilogue: exp2 + row/col partials + diag capture ----
    const int gc = colBase + t * 16 + li;       // this lane's column
    float cs = 0.0f;
    const bool isDiag = diagWave && ((t >> 2) == (band & 15));
    #pragma unroll
    for (int m = 0; m < 4; ++m) {
      #pragma unroll
      for (int j = 0; j < 4; ++j) {
        const float s = acc[m][j];
        const float e = fexp2(s);
        rsum[m][j] += e;
        cs += e;
        if (isDiag && (rowBase + m * 16 + grp * 4 + j == gc)) diag8[gc] = s;
      }
    }
    cs += __shfl_xor(cs, 16);
    cs += __shfl_xor(cs, 32);
    if (grp == 0) {
      if (use_scratch) colpartW[(size_t)band * N_ROWS + gc] = cs;
      else atomicAdd(&colsumG[gc], cs);
    }

    #pragma unroll
    for (int ks = 0; ks < 8; ++ks) bc[ks] = bn[ks];
  }

  // ---- row-sum writeout (each wave owns its 64 rows in this chunk) ----
  #pragma unroll
  for (int m = 0; m < 4; ++m) {
    #pragma unroll
    for (int j = 0; j < 4; ++j) {
      float v = rsum[m][j];
      v += __shfl_xor(v, 1); v += __shfl_xor(v, 2);
      v += __shfl_xor(v, 4); v += __shfl_xor(v, 8);
      if (li == 0) {
        const int r = rowBase + m * 16 + grp * 4 + j;
        if (use_scratch) rowpart[(size_t)chunk * N_ROWS + r] = v;
        else atomicAdd(&rowsumG[r], v);
      }
    }
  }
}

// ------------------------------------------------------------------
// Kernel 3: reduce partials + final loss.
// ------------------------------------------------------------------
__global__ __launch_bounds__(256) void finalize_kernel(
    const float* __restrict__ rowpart, const float* __restrict__ colpartW,
    const float* __restrict__ rowsumG, const float* __restrict__ colsumG,
    const float* __restrict__ diag8, const float* __restrict__ diagF,
    float* __restrict__ out, int use_scratch) {
  __shared__ float red[4];
  const int i = blockIdx.x * 256 + threadIdx.x;
  float rs, cs;
  if (use_scratch) {
    rs = 0.0f;
    #pragma unroll
    for (int c = 0; c < 16; ++c) rs += rowpart[(size_t)c * N_ROWS + i];
    cs = 0.0f;
    #pragma unroll 8
    for (int b = 0; b < 256; ++b) cs += colpartW[(size_t)b * N_ROWS + i];
  } else {
    rs = rowsumG[i];
    cs = colsumG[i];
  }
  const float e8 = fexp2(diag8[i]);           // matches gemm's exp2 exactly
  const float mm = __expf(diagF[i] - MARGINF);
  float v = mm / (mm + rs - e8) + mm / (mm + cs - e8);
  #pragma unroll
  for (int off = 32; off; off >>= 1) v += __shfl_xor(v, off);
  if ((threadIdx.x & 63) == 0) red[threadIdx.x >> 6] = v;
  __syncthreads();
  if (threadIdx.x == 0) {
    const float t = red[0] + red[1] + red[2] + red[3];
    atomicAdd(out, -t / (float)N_ROWS);
  }
}

// ------------------------------------------------------------------
extern "C" void kernel_launch(void* const* d_in, const int* in_sizes, int n_in,
                              void* d_out, int out_size, void* d_ws, size_t ws_size,
                              hipStream_t stream) {
  const float* x = (const float*)d_in[0];
  const float* y = (const float*)d_in[1];
  char* ws = (char*)d_ws;
  unsigned char* xn8 = (unsigned char*)ws;                   // 4 MiB
  unsigned char* yn8 = (unsigned char*)(ws + (4u << 20));    // 4 MiB
  float* diag8    = (float*)(ws + (8u << 20));               // 64 KiB
  float* diagF    = (float*)(ws + (8u << 20) + 65536);       // 64 KiB
  float* rowpart  = (float*)(ws + (8u << 20) + 131072);      // 1 MiB [16][N]
  float* colpartW = (float*)(ws + (8u << 20) + 131072 + (1u << 20));  // 16 MiB [256][N]
  float* rowsumG = rowpart;                                  // fallback aliases
  float* colsumG = rowpart + N_ROWS;
  const size_t need_scratch = (8u << 20) + 131072 + (1u << 20) + (16u << 20);
  const int use_scratch = (ws_size >= need_scratch) ? 1 : 0;

  hipMemsetAsync(d_out, 0, sizeof(float), stream);
  if (!use_scratch) hipMemsetAsync(rowsumG, 0, 2 * N_ROWS * sizeof(float), stream);
  normalize_kernel<<<4096, 256, 0, stream>>>(x, y, (unsigned int*)xn8,
                                             (unsigned int*)yn8, diagF);
  gemm_exp_kernel<<<1024, 256, 0, stream>>>(xn8, yn8, diag8, rowpart, colpartW,
                                            rowsumG, colsumG, use_scratch);
  finalize_kernel<<<64, 256, 0, stream>>>(rowpart, colpartW, rowsumG, colsumG,
                                          diag8, diagF, (float*)d_out, use_scratch);
}

// Round 10
// 170.126 us; speedup vs baseline: 1.6672x; 1.6672x over previous
//
#include <hip/hip_runtime.h>

#define N_ROWS 16384
#define DIM 256
#define MARGINF 0.3f
#define CH 2048
#define TILES 32
#define LOG2E 1.44269504089f

typedef float f32x4 __attribute__((ext_vector_type(4)));
typedef long lng;

__device__ __forceinline__ float fexp2(float x) {
#if __has_builtin(__builtin_amdgcn_exp2f)
  return __builtin_amdgcn_exp2f(x);
#else
  return exp2f(x);
#endif
}

// ------------------------------------------------------------------
// float -> OCP e4m3fn (manual fallback)
// ------------------------------------------------------------------
__device__ __forceinline__ unsigned char to_e4m3(float f) {
  unsigned u = __float_as_uint(f);
  unsigned sign = (u >> 24) & 0x80u;
  float a = fabsf(f);
  if (a >= 448.0f) return (unsigned char)(sign | 0x7eu);
  if (a < 0.015625f) {
    int q = (int)(a * 512.0f + 0.5f);
    return (unsigned char)(sign | (unsigned)q);
  }
  int e;
  float m = frexpf(a, &e);
  float mant = 2.0f * m;
  int e8 = e - 1;
  int mb = (int)(mant * 8.0f + 0.5f) - 8;
  if (mb == 8) { mb = 0; ++e8; if (e8 > 8) return (unsigned char)(sign | 0x7eu); }
  return (unsigned char)(sign | (unsigned)((e8 + 7) << 3) | (unsigned)mb);
}

__device__ __forceinline__ unsigned int pack4_e4m3(float a, float b, float c, float d) {
#if __has_builtin(__builtin_amdgcn_cvt_pk_fp8_f32)
  int lo = __builtin_amdgcn_cvt_pk_fp8_f32(a, b, 0, false);
  int r = __builtin_amdgcn_cvt_pk_fp8_f32(c, d, lo, true);
  return (unsigned int)r;
#else
  return (unsigned int)to_e4m3(a) | ((unsigned int)to_e4m3(b) << 8) |
         ((unsigned int)to_e4m3(c) << 16) | ((unsigned int)to_e4m3(d) << 24);
#endif
}

// ------------------------------------------------------------------
// Kernel 1: norms + exact fp32 diag cosine + fp8 rows.
// x-side pre-scaled by log2(e) so the GEMM's exp(S) = exp2(S').
// ------------------------------------------------------------------
__global__ __launch_bounds__(256) void normalize_kernel(
    const float* __restrict__ x, const float* __restrict__ y,
    unsigned int* __restrict__ xn8, unsigned int* __restrict__ yn8,
    float* __restrict__ diagF) {
  const int wid = threadIdx.x >> 6;
  const int lane = threadIdx.x & 63;
  const int r = blockIdx.x * 4 + wid;  // 0..16383
  const float4 vx = *reinterpret_cast<const float4*>(x + (size_t)r * DIM + lane * 4);
  const float4 vy = *reinterpret_cast<const float4*>(y + (size_t)r * DIM + lane * 4);
  float sx = vx.x * vx.x + vx.y * vx.y + vx.z * vx.z + vx.w * vx.w;
  float sy = vy.x * vy.x + vy.y * vy.y + vy.z * vy.z + vy.w * vy.w;
  float sxy = vx.x * vy.x + vx.y * vy.y + vx.z * vy.z + vx.w * vy.w;
  #pragma unroll
  for (int off = 32; off; off >>= 1) {
    sx += __shfl_xor(sx, off);
    sy += __shfl_xor(sy, off);
    sxy += __shfl_xor(sxy, off);
  }
  const float scx = LOG2E / fmaxf(sqrtf(sx), 1e-8f);   // log2e folded into A
  const float scy = 1.0f / fmaxf(sqrtf(sy), 1e-8f);
  if (lane == 0) diagF[r] = sxy * (scx / LOG2E) * scy;
  xn8[(size_t)r * 64 + lane] = pack4_e4m3(vx.x * scx, vx.y * scx, vx.z * scx, vx.w * scx);
  yn8[(size_t)r * 64 + lane] = pack4_e4m3(vy.x * scy, vy.y * scy, vy.z * scy, vy.w * scy);
}

// ------------------------------------------------------------------
// Stage one 64-col x 256-K fp8 panel (16 KB) into LDS.
// Granule XOR-swizzle (col&7) on the GLOBAL side; linear LDS dest
// (global_load_lds requirement). [verbatim from R4/R5 - passed]
// ------------------------------------------------------------------
__device__ __forceinline__ void stage_panel(const unsigned char* __restrict__ src,
                                            int colBase, unsigned char* ldsBase, int tid) {
  const int wid = tid >> 6;
  #pragma unroll
  for (int it = 0; it < 4; ++it) {
    const int id = it * 256 + tid;      // 1024 x 16B granules
    const int col = id >> 4;            // 0..63
    const int slot = id & 15;
    const int srcg = slot ^ (col & 7);
    const unsigned char* gp = src + (size_t)(colBase + col) * DIM + srcg * 16;
    unsigned char* l = ldsBase + (size_t)(it * 256 + wid * 64) * 16;  // wave-uniform
    __builtin_amdgcn_global_load_lds(
        (const __attribute__((address_space(1))) unsigned int*)gp,
        (__attribute__((address_space(3))) unsigned int*)l, 16, 0, 0);
  }
}

// ------------------------------------------------------------------
// Kernel 2: fp8 GEMM + exp2. 128-row band x 2048-col chunk, 4 waves
// (2wm x 2wn), wave tile 64x32, A in regs. R4's proven 2-phase flow
// (stage(t+1) at top, ONE __syncthreads at bottom). LDS exactly
// 32 KB -> 4 blocks/CU co-resident (vs 40-48KB -> 2: alloc rounds
// >32KB up to 64KB). 4 independent barrier domains per SIMD.
// ------------------------------------------------------------------
__global__ __launch_bounds__(256, 3) void gemm_exp_kernel(
    const unsigned char* __restrict__ xn8, const unsigned char* __restrict__ yn8,
    float* __restrict__ diag8, float* __restrict__ rowpart,
    float* __restrict__ colpartW, float* __restrict__ rowsumG,
    float* __restrict__ colsumG, int use_scratch) {
  __shared__ unsigned char ldsB[2][16384];  // exactly 32 KB

  const int tid = threadIdx.x;
  const int lane = tid & 63;
  const int wid = tid >> 6;
  const int wm = wid >> 1, wn = wid & 1;
  const int grp = lane >> 4, li = lane & 15;

  const int bid = blockIdx.x;
  const int chunk = bid & 7;        // XCD round-robin
  const int band = bid >> 3;        // 0..127
  const int rowBase = band * 128;
  const int colBase = chunk * CH;

  // ---- A band -> registers (fp8: 8B per ks-frag) [verbatim R4/R5] ----
  lng a[4][8];
  #pragma unroll
  for (int m = 0; m < 4; ++m)
    #pragma unroll
    for (int ks = 0; ks < 8; ++ks) {
      const int row = rowBase + wm * 64 + m * 16 + li;
      a[m][ks] = *reinterpret_cast<const lng*>(
          xn8 + (size_t)row * DIM + ks * 32 + grp * 8);
    }

  stage_panel(yn8, colBase, &ldsB[0][0], tid);
  __syncthreads();

  float rsum[4][4];
  #pragma unroll
  for (int m = 0; m < 4; ++m)
    #pragma unroll
    for (int j = 0; j < 4; ++j) rsum[m][j] = 0.0f;

  const int bandDelta = band - chunk * 16;  // diag stripe iff in [0,16)

  for (int t = 0; t < TILES; ++t) {
    if (t + 1 < TILES)
      stage_panel(yn8, colBase + (t + 1) * 64, &ldsB[(t + 1) & 1][0], tid);

    const unsigned char* Bp = &ldsB[t & 1][0];
    f32x4 acc[4][2];
    #pragma unroll
    for (int m = 0; m < 4; ++m) { acc[m][0] = (f32x4)(0.0f); acc[m][1] = (f32x4)(0.0f); }

    const int col0 = wn * 32 + li;
    const int off = (grp & 1) * 8;
    __builtin_amdgcn_s_setprio(1);
    #pragma unroll
    for (int ks = 0; ks < 8; ++ks) {
      const int g = 2 * ks + (grp >> 1);
      const lng b0 = *reinterpret_cast<const lng*>(
          Bp + (size_t)col0 * 256 + ((g ^ (li & 7)) * 16) + off);
      const lng b1 = *reinterpret_cast<const lng*>(
          Bp + (size_t)(col0 + 16) * 256 + ((g ^ (li & 7)) * 16) + off);
      #pragma unroll
      for (int m = 0; m < 4; ++m) {
        acc[m][0] = __builtin_amdgcn_mfma_f32_16x16x32_fp8_fp8(a[m][ks], b0, acc[m][0], 0, 0, 0);
        acc[m][1] = __builtin_amdgcn_mfma_f32_16x16x32_fp8_fp8(a[m][ks], b1, acc[m][1], 0, 0, 0);
      }
    }
    __builtin_amdgcn_s_setprio(0);

    // epilogue: exp2 + row/col partials + diag capture [verbatim R5]
    float cs0 = 0.0f, cs1 = 0.0f;
    const bool maybeDiag = (bandDelta == (t >> 1));
    #pragma unroll
    for (int m = 0; m < 4; ++m) {
      #pragma unroll
      for (int j = 0; j < 4; ++j) {
        const float s0 = acc[m][0][j];
        const float s1 = acc[m][1][j];
        const float e0 = fexp2(s0);
        const float e1 = fexp2(s1);
        rsum[m][j] += e0 + e1;
        cs0 += e0;
        cs1 += e1;
        if (maybeDiag) {
          const int rg = rowBase + wm * 64 + m * 16 + grp * 4 + j;
          const int cg = colBase + t * 64 + wn * 32 + li;
          if (rg == cg) diag8[rg] = s0;
          if (rg == cg + 16) diag8[rg] = s1;
        }
      }
    }
    cs0 += __shfl_xor(cs0, 16); cs0 += __shfl_xor(cs0, 32);
    cs1 += __shfl_xor(cs1, 16); cs1 += __shfl_xor(cs1, 32);
    if (grp == 0) {
      const int c = t * 64 + wn * 32 + li;
      if (use_scratch) {
        colpartW[((size_t)(wm * 128 + band)) * N_ROWS + colBase + c] = cs0;
        colpartW[((size_t)(wm * 128 + band)) * N_ROWS + colBase + c + 16] = cs1;
      } else {
        atomicAdd(&colsumG[colBase + c], cs0);
        atomicAdd(&colsumG[colBase + c + 16], cs1);
      }
    }
    __syncthreads();
  }

  // ---- cross-wave row-sum reduction (reuse ldsB) [verbatim R5] ----
  float* rowTmp = reinterpret_cast<float*>(&ldsB[0][0]);  // [2 wn][128]
  #pragma unroll
  for (int m = 0; m < 4; ++m) {
    #pragma unroll
    for (int j = 0; j < 4; ++j) {
      float v = rsum[m][j];
      v += __shfl_xor(v, 1); v += __shfl_xor(v, 2);
      v += __shfl_xor(v, 4); v += __shfl_xor(v, 8);
      if (li == 0) rowTmp[wn * 128 + wm * 64 + m * 16 + grp * 4 + j] = v;
    }
  }
  __syncthreads();
  if (tid < 128) {
    const float v = rowTmp[tid] + rowTmp[128 + tid];
    if (use_scratch) rowpart[(size_t)chunk * N_ROWS + rowBase + tid] = v;
    else atomicAdd(&rowsumG[rowBase + tid], v);
  }
}

// ------------------------------------------------------------------
// Kernel 3: reduce partials + final loss. [verbatim R5]
// ------------------------------------------------------------------
__global__ __launch_bounds__(256) void finalize_kernel(
    const float* __restrict__ rowpart, const float* __restrict__ colpartW,
    const float* __restrict__ rowsumG, const float* __restrict__ colsumG,
    const float* __restrict__ diag8, const float* __restrict__ diagF,
    float* __restrict__ out, int use_scratch) {
  __shared__ float red[4];
  const int i = blockIdx.x * 256 + threadIdx.x;
  float rs, cs;
  if (use_scratch) {
    rs = 0.0f;
    #pragma unroll
    for (int c = 0; c < 8; ++c) rs += rowpart[(size_t)c * N_ROWS + i];
    cs = 0.0f;
    #pragma unroll 8
    for (int b = 0; b < 256; ++b) cs += colpartW[(size_t)b * N_ROWS + i];
  } else {
    rs = rowsumG[i];
    cs = colsumG[i];
  }
  const float e8 = fexp2(diag8[i]);           // matches gemm's exp2 exactly
  const float mm = __expf(diagF[i] - MARGINF);
  float v = mm / (mm + rs - e8) + mm / (mm + cs - e8);
  #pragma unroll
  for (int off = 32; off; off >>= 1) v += __shfl_xor(v, off);
  if ((threadIdx.x & 63) == 0) red[threadIdx.x >> 6] = v;
  __syncthreads();
  if (threadIdx.x == 0) {
    const float t = red[0] + red[1] + red[2] + red[3];
    atomicAdd(out, -t / (float)N_ROWS);
  }
}

// ------------------------------------------------------------------
extern "C" void kernel_launch(void* const* d_in, const int* in_sizes, int n_in,
                              void* d_out, int out_size, void* d_ws, size_t ws_size,
                              hipStream_t stream) {
  const float* x = (const float*)d_in[0];
  const float* y = (const float*)d_in[1];
  char* ws = (char*)d_ws;
  unsigned char* xn8 = (unsigned char*)ws;                   // 4 MiB
  unsigned char* yn8 = (unsigned char*)(ws + (4u << 20));    // 4 MiB
  float* diag8    = (float*)(ws + (8u << 20));               // 64 KiB
  float* diagF    = (float*)(ws + (8u << 20) + 65536);       // 64 KiB
  float* rowpart  = (float*)(ws + (8u << 20) + 131072);      // 512 KiB [8][N]
  float* colpartW = (float*)(ws + (8u << 20) + 131072 + 524288);  // 16 MiB [256][N]
  float* rowsumG = rowpart;                                  // fallback aliases
  float* colsumG = rowpart + N_ROWS;
  const size_t need_scratch = (8u << 20) + 131072 + 524288 + (16u << 20);
  const int use_scratch = (ws_size >= need_scratch) ? 1 : 0;

  hipMemsetAsync(d_out, 0, sizeof(float), stream);
  if (!use_scratch) hipMemsetAsync(rowsumG, 0, 2 * N_ROWS * sizeof(float), stream);
  normalize_kernel<<<4096, 256, 0, stream>>>(x, y, (unsigned int*)xn8,
                                             (unsigned int*)yn8, diagF);
  gemm_exp_kernel<<<1024, 256, 0, stream>>>(xn8, yn8, diag8, rowpart, colpartW,
                                            rowsumG, colsumG, use_scratch);
  finalize_kernel<<<64, 256, 0, stream>>>(rowpart, colpartW, rowsumG, colsumG,
                                          diag8, diagF, (float*)d_out, use_scratch);
}